// Round 1
// baseline (4127.188 us; speedup 1.0000x reference)
//
#include <hip/hip_runtime.h>

#define Hh 96
#define Ww 96
#define HW 9216
#define NPIX 589824   // 64*96*96

// ---------------------------------------------------------------------------
// Generic 3x3 conv, pad=1, stride=1, fp32.
//  - input channels: first ic0 from in0, remainder from in1 (free concat)
//  - block: 256 threads = 64 pixels (8x8 tile) x 4 oc-quads; 4 out ch / thread
//  - grid: (144 spatial tiles, OC/16)
//  - epilogue: v = acc + bias; if lrelu v=lrelu(v); v*=alpha; if r1 v+=beta*r1
// ---------------------------------------------------------------------------
__global__ __launch_bounds__(256) void conv3x3_k(
    const float* __restrict__ in0, int ic0,
    const float* __restrict__ in1,
    const float* __restrict__ wgt,     // [OC][IC][3][3]
    const float* __restrict__ bias,    // [OC]
    int IC,
    float* __restrict__ out,           // [OC][96][96]
    int do_lrelu, float alpha,
    const float* __restrict__ r1, float beta)
{
    const int tile = blockIdx.x;            // 0..143
    const int tx0 = (tile % 12) * 8;
    const int ty0 = (tile / 12) * 8;
    const int ocg = blockIdx.y * 16;
    const int tid = threadIdx.x;
    const int px  = tid & 63;
    const int ocq = tid >> 6;                // 0..3
    const int yy  = px >> 3, xx = px & 7;

    __shared__ float s_in[16][10][10];
    __shared__ float s_w[16][16][9];

    float acc[4] = {0.f, 0.f, 0.f, 0.f};

    for (int icb = 0; icb < IC; icb += 16) {
        int ch = IC - icb; if (ch > 16) ch = 16;
        // stage input tile (10x10 halo) for this channel chunk
        for (int i = tid; i < ch * 100; i += 256) {
            int c  = i / 100, rr = i % 100;
            int ry = rr / 10,  rx = rr % 10;
            int iy = ty0 - 1 + ry, ix = tx0 - 1 + rx;
            float v = 0.f;
            if (iy >= 0 && iy < Hh && ix >= 0 && ix < Ww) {
                int gc = icb + c;
                const float* src = (gc < ic0) ? (in0 + (size_t)gc * HW)
                                              : (in1 + (size_t)(gc - ic0) * HW);
                v = src[iy * Ww + ix];
            }
            s_in[c][ry][rx] = v;
        }
        // stage weights for this chunk (16 oc x ch x 9)
        for (int i = tid; i < 16 * ch * 9; i += 256) {
            int oc  = i / (ch * 9);
            int rem = i - oc * ch * 9;
            int c   = rem / 9, tap = rem % 9;
            s_w[oc][c][tap] = wgt[((size_t)(ocg + oc) * IC + icb + c) * 9 + tap];
        }
        __syncthreads();

        for (int c = 0; c < ch; ++c) {
            #pragma unroll
            for (int tap = 0; tap < 9; ++tap) {
                float v = s_in[c][yy + tap / 3][xx + tap % 3];
                #pragma unroll
                for (int o = 0; o < 4; ++o)
                    acc[o] += v * s_w[ocq * 4 + o][c][tap];
            }
        }
        __syncthreads();
    }

    const int y = ty0 + yy, x = tx0 + xx;
    #pragma unroll
    for (int o = 0; o < 4; ++o) {
        int oc = ocg + ocq * 4 + o;
        float v = acc[o] + bias[oc];
        if (do_lrelu) v = (v > 0.f) ? v : 0.2f * v;
        v *= alpha;
        size_t oi = (size_t)oc * HW + (size_t)y * Ww + x;
        if (r1) v += beta * r1[oi];
        out[oi] = v;
    }
}

// dst[i] = a*x[i] + b*y[i]   (y may be null, y may alias dst)
__global__ __launch_bounds__(256) void axpby_k(
    float* __restrict__ dst, const float* __restrict__ x, float a,
    const float* __restrict__ y, float b, int n)
{
    int i = blockIdx.x * 256 + threadIdx.x;
    if (i < n) {
        float v = a * x[i];
        if (y) v += b * y[i];
        dst[i] = v;
    }
}

// ---------------------------------------------------------------------------
// Dynamic-filter MLP collapsed to 192 distinct rows (winp[p]=(p%192,p%192,2)).
// Produces WtT[f][t], f in [0,1728), t in [0,192)  (transposed for coalesced
// reads in the gather kernel).
// ---------------------------------------------------------------------------
__global__ __launch_bounds__(256) void mlp_weights_k(
    const float* __restrict__ fc1_w,   // [3][256]
    const float* __restrict__ fc1_b,   // [256]
    const float* __restrict__ fc2_w,   // [256][1728]
    const float* __restrict__ fc2_b,   // [1728]
    float* __restrict__ WtT)           // [1728][192]
{
    const int t   = blockIdx.x;        // 0..191
    const int tid = threadIdx.x;       // 256
    __shared__ float h1[256];
    float tt = (float)t;
    float v = tt * fc1_w[tid] + tt * fc1_w[256 + tid] + 2.0f * fc1_w[512 + tid]
              + fc1_b[tid];
    h1[tid] = (v > 0.f) ? v : 0.2f * v;
    __syncthreads();
    for (int f = tid; f < 1728; f += 256) {
        float acc = fc2_b[f];
        for (int j = 0; j < 256; ++j)
            acc += h1[j] * fc2_w[(size_t)j * 1728 + f];
        WtT[(size_t)f * 192 + t] = acc;
    }
}

// ---------------------------------------------------------------------------
// out[c][h][w] = sum_{k,di,dj} WtT[(w%3)*576 + k*9 + di*3 + dj][t]
//                              * featpad[k][h/2+di][w/2+dj]
// t = (h%3)*64 + w/3 ; identical across c (property of the reference's
// coordinate construction). oH=oW=192, sf=2.
// One thread per (h, a=w/3); computes q=0..2 and writes 3 channels.
// ---------------------------------------------------------------------------
__global__ __launch_bounds__(256) void dynfilter_k(
    const float* __restrict__ feat,    // [64][96][96]
    const float* __restrict__ WtT,     // [1728][192]
    float* __restrict__ out)           // [3][192][192]
{
    int idx = blockIdx.x * 256 + threadIdx.x;   // 192*64 = 12288
    if (idx >= 192 * 64) return;
    int h = idx >> 6, a = idx & 63;
    int t = (h % 3) * 64 + a;
    float val[3];
    #pragma unroll
    for (int q = 0; q < 3; ++q) {
        int w  = 3 * a + q;
        int iy0 = h / 2 - 1, ix0 = w / 2 - 1;
        float acc = 0.f;
        for (int k = 0; k < 64; ++k) {
            #pragma unroll
            for (int di = 0; di < 3; ++di) {
                int yv = iy0 + di;
                if (yv < 0 || yv >= Hh) continue;
                #pragma unroll
                for (int dj = 0; dj < 3; ++dj) {
                    int xv = ix0 + dj;
                    if (xv < 0 || xv >= Ww) continue;
                    float fv = feat[(size_t)k * HW + yv * Ww + xv];
                    float wv = WtT[(size_t)(q * 576 + k * 9 + di * 3 + dj) * 192 + t];
                    acc += fv * wv;
                }
            }
        }
        val[q] = acc;
    }
    #pragma unroll
    for (int c = 0; c < 3; ++c)
        #pragma unroll
        for (int q = 0; q < 3; ++q)
            out[(size_t)c * 36864 + (size_t)h * 192 + 3 * a + q] = val[q];
}

// ---------------------------------------------------------------------------
extern "C" void kernel_launch(void* const* d_in, const int* in_sizes, int n_in,
                              void* d_out, int out_size, void* d_ws, size_t ws_size,
                              hipStream_t stream)
{
    const float* x     = (const float*)d_in[0];
    const float* c1_w  = (const float*)d_in[1];
    const float* c1_b  = (const float*)d_in[2];
    const float* dbw[5] = {(const float*)d_in[3], (const float*)d_in[5],
                           (const float*)d_in[7], (const float*)d_in[9],
                           (const float*)d_in[11]};
    const float* dbb[5] = {(const float*)d_in[4], (const float*)d_in[6],
                           (const float*)d_in[8], (const float*)d_in[10],
                           (const float*)d_in[12]};
    const float* c2_w  = (const float*)d_in[13];
    const float* c2_b  = (const float*)d_in[14];
    const float* fc1_w = (const float*)d_in[15];
    const float* fc1_b = (const float*)d_in[16];
    const float* fc2_w = (const float*)d_in[17];
    const float* fc2_b = (const float*)d_in[18];

    float* ws   = (float*)d_ws;
    float* x0   = ws;
    float* feat = ws + (size_t)NPIX;
    float* hA   = ws + 2 * (size_t)NPIX;
    float* hB   = ws + 3 * (size_t)NPIX;
    float* gbuf = ws + 4 * (size_t)NPIX;
    float* WtT  = ws + 5 * (size_t)NPIX;   // 1728*192 floats

    const int ICs[5]     = {64, 80, 96, 112, 128};
    const int wstride[5] = {9216, 11520, 13824, 16128, 73728};
    const int bstride[5] = {16, 16, 16, 16, 64};

    const int EB = (NPIX + 255) / 256;

    // c1: 3 -> 64, plain bias
    conv3x3_k<<<dim3(144, 4), 256, 0, stream>>>(x, 3, nullptr, c1_w, c1_b, 3,
                                                x0, 0, 1.f, nullptr, 0.f);
    // feat = x0
    axpby_k<<<EB, 256, 0, stream>>>(feat, x0, 1.f, nullptr, 0.f, NPIX);

    for (int blk = 0; blk < 4; ++blk) {
        // h = feat (feat stays as feat_in for the RRDB residual)
        axpby_k<<<EB, 256, 0, stream>>>(hA, feat, 1.f, nullptr, 0.f, NPIX);
        for (int db = 0; db < 3; ++db) {
            int d = blk * 3 + db;
            float* base  = (db & 1) ? hB : hA;
            float* other = (db & 1) ? hA : hB;
            // convs 1..4 (lrelu, 16 out ch) into gbuf growth channels
            for (int cv = 0; cv < 4; ++cv) {
                conv3x3_k<<<dim3(144, 1), 256, 0, stream>>>(
                    base, 64, gbuf,
                    dbw[cv] + (size_t)d * wstride[cv],
                    dbb[cv] + (size_t)d * bstride[cv],
                    ICs[cv], gbuf + (size_t)cv * 16 * HW,
                    1, 1.f, nullptr, 0.f);
            }
            // conv5 (no lrelu): h_new = conv*0.2 + h
            conv3x3_k<<<dim3(144, 4), 256, 0, stream>>>(
                base, 64, gbuf,
                dbw[4] + (size_t)d * wstride[4],
                dbb[4] + (size_t)d * bstride[4],
                128, other, 0, 0.2f, base, 1.f);
        }
        // feat = h3*0.2 + feat_in   (h3 is in hB after db0,db1,db2)
        axpby_k<<<EB, 256, 0, stream>>>(feat, hB, 0.2f, feat, 1.f, NPIX);
    }

    // feat_final = conv(feat, c2) + x0  -> hA
    conv3x3_k<<<dim3(144, 4), 256, 0, stream>>>(feat, 64, nullptr, c2_w, c2_b,
                                                64, hA, 0, 1.f, x0, 1.f);

    // dynamic-filter weights (192 distinct rows), transposed
    mlp_weights_k<<<192, 256, 0, stream>>>(fc1_w, fc1_b, fc2_w, fc2_b, WtT);

    // final gather-multiply-reduce
    dynfilter_k<<<48, 256, 0, stream>>>(hA, WtT, (float*)d_out);
}

// Round 2
// 2735.345 us; speedup vs baseline: 1.5088x; 1.5088x over previous
//
#include <hip/hip_runtime.h>

#define Hh 96
#define Ww 96
#define HW 9216
#define NPIX 589824   // 64*96*96

// ---------------------------------------------------------------------------
// 3x3 conv, pad=1, stride=1, fp32, 2x2 register blocking.
//  - block: 256 threads = 16 spatial (each 2x2 px of an 8x8 tile) x 16 oc
//  - grid: (144 spatial tiles, OC/16)
//  - input channels: first ic0 from in0, remainder from in1 (free concat)
//  - epilogue: v = act(acc + bias); v = alpha*v + beta*r1 + gamma*r2
// ---------------------------------------------------------------------------
__global__ __launch_bounds__(256) void conv3x3_k(
    const float* __restrict__ in0, int ic0,
    const float* __restrict__ in1,
    const float* __restrict__ wgt,     // [OC][IC][3][3]
    const float* __restrict__ bias,    // [OC]
    int IC,
    float* out,                        // [OC][96][96]  (no restrict: may alias r2)
    int do_lrelu, float alpha,
    const float* r1, float beta,
    const float* r2, float gamma)
{
    const int tile = blockIdx.x;            // 0..143
    const int tx0 = (tile % 12) * 8;
    const int ty0 = (tile / 12) * 8;
    const int ocg = blockIdx.y * 16;
    const int tid = threadIdx.x;
    const int sp  = tid & 15;                // 4x4 grid of 2x2-px patches
    const int ocl = tid >> 4;                // 0..15
    const int y2  = (sp >> 2) * 2;
    const int x2  = (sp & 3) * 2;

    __shared__ float s_in[16][10][12];       // padded stride 12: bank-clean
    __shared__ float s_w[16 * 9 * 16];       // [c][tap][ocl]

    float acc[2][2] = {{0.f, 0.f}, {0.f, 0.f}};

    for (int icb = 0; icb < IC; icb += 16) {
        int ch = IC - icb; if (ch > 16) ch = 16;
        // stage input tile (10x10 halo) for this channel chunk
        for (int i = tid; i < ch * 100; i += 256) {
            int c  = i / 100, rr = i - c * 100;
            int ry = rr / 10,  rx = rr - ry * 10;
            int iy = ty0 - 1 + ry, ix = tx0 - 1 + rx;
            float v = 0.f;
            if (iy >= 0 && iy < Hh && ix >= 0 && ix < Ww) {
                int gc = icb + c;
                const float* src = (gc < ic0) ? (in0 + (size_t)gc * HW)
                                              : (in1 + (size_t)(gc - ic0) * HW);
                v = src[iy * Ww + ix];
            }
            s_in[c][ry][rx] = v;
        }
        // stage weights [c][tap][ocl], LDS-write coalesced
        for (int i = tid; i < ch * 144; i += 256) {
            int o  = i & 15;
            int ct = i >> 4;                 // c*9 + tap
            int c  = ct / 9, tap = ct - c * 9;
            s_w[i] = wgt[((size_t)(ocg + o) * IC + icb + c) * 9 + tap];
        }
        __syncthreads();

        for (int c = 0; c < ch; ++c) {
            float r[4][4];
            #pragma unroll
            for (int ii = 0; ii < 4; ++ii) {
                const float2 a = *reinterpret_cast<const float2*>(&s_in[c][y2 + ii][x2]);
                const float2 b = *reinterpret_cast<const float2*>(&s_in[c][y2 + ii][x2 + 2]);
                r[ii][0] = a.x; r[ii][1] = a.y; r[ii][2] = b.x; r[ii][3] = b.y;
            }
            const float* wp = &s_w[c * 144 + ocl];
            #pragma unroll
            for (int i = 0; i < 3; ++i) {
                #pragma unroll
                for (int j = 0; j < 3; ++j) {
                    float wv = wp[(i * 3 + j) * 16];
                    acc[0][0] += wv * r[i][j];
                    acc[0][1] += wv * r[i][j + 1];
                    acc[1][0] += wv * r[i + 1][j];
                    acc[1][1] += wv * r[i + 1][j + 1];
                }
            }
        }
        __syncthreads();
    }

    const int oc = ocg + ocl;
    const float b = bias[oc];
    #pragma unroll
    for (int dy = 0; dy < 2; ++dy) {
        #pragma unroll
        for (int dx = 0; dx < 2; ++dx) {
            float v = acc[dy][dx] + b;
            if (do_lrelu) v = (v > 0.f) ? v : 0.2f * v;
            v *= alpha;
            size_t oi = (size_t)oc * HW + (size_t)(ty0 + y2 + dy) * Ww + (tx0 + x2 + dx);
            if (r1) v += beta * r1[oi];
            if (r2) v += gamma * r2[oi];
            out[oi] = v;
        }
    }
}

// ---------------------------------------------------------------------------
// Dynamic-filter MLP collapsed to 192 distinct rows (winp[p]=(p%192,p%192,2)).
// Produces WtT[f][t], f in [0,1728), t in [0,192).
// ---------------------------------------------------------------------------
__global__ __launch_bounds__(256) void mlp_weights_k(
    const float* __restrict__ fc1_w,   // [3][256]
    const float* __restrict__ fc1_b,   // [256]
    const float* __restrict__ fc2_w,   // [256][1728]
    const float* __restrict__ fc2_b,   // [1728]
    float* __restrict__ WtT)           // [1728][192]
{
    const int t   = blockIdx.x;        // 0..191
    const int tid = threadIdx.x;       // 256
    __shared__ float h1[256];
    float tt = (float)t;
    float v = tt * fc1_w[tid] + tt * fc1_w[256 + tid] + 2.0f * fc1_w[512 + tid]
              + fc1_b[tid];
    h1[tid] = (v > 0.f) ? v : 0.2f * v;
    __syncthreads();
    for (int f = tid; f < 1728; f += 256) {
        float acc = fc2_b[f];
        for (int j = 0; j < 256; ++j)
            acc += h1[j] * fc2_w[(size_t)j * 1728 + f];
        WtT[(size_t)f * 192 + t] = acc;
    }
}

// ---------------------------------------------------------------------------
// out[c][h][w] = sum_{k,di,dj} WtT[(w%3)*576 + k*9 + di*3 + dj][t]
//                              * featpad[k][h/2+di][w/2+dj]
// t = (h%3)*64 + w/3 ; identical across c.  oH=oW=192, sf=2.
// Block = (h, 64-wide w segment); 256 thr = 64 w x 4 k-chunks; LDS reduce.
// ---------------------------------------------------------------------------
__global__ __launch_bounds__(256) void dynfilter_k(
    const float* __restrict__ feat,    // [64][96][96]
    const float* __restrict__ WtT,     // [1728][192]
    float* __restrict__ out)           // [3][192][192]
{
    const int h   = blockIdx.y;        // 0..191
    const int w0  = blockIdx.x * 64;   // 0,64,128
    const int tid = threadIdx.x;
    const int lw  = tid & 63, kc = tid >> 6;
    const int ybase = h / 2 - 1;
    const int x0lo  = w0 / 2 - 1;

    __shared__ float s_f[64][3][36];   // [k][di][col], 34 used
    __shared__ float s_red[4][64];

    for (int i = tid; i < 64 * 3 * 34; i += 256) {
        int k = i / 102, rem = i - k * 102;
        int di = rem / 34, col = rem - di * 34;
        int yv = ybase + di, xv = x0lo + col;
        float v = 0.f;
        if (yv >= 0 && yv < Hh && xv >= 0 && xv < Ww)
            v = feat[(size_t)k * HW + yv * Ww + xv];
        s_f[k][di][col] = v;
    }
    __syncthreads();

    const int w = w0 + lw;
    const int q = w % 3;
    const int t = (h % 3) * 64 + w / 3;
    const int lx = (w / 2 - 1) - x0lo;       // 0..31
    const float* Wp = WtT + (size_t)(q * 576 + kc * 144) * 192 + t;
    float acc = 0.f;
    for (int k = 0; k < 16; ++k) {
        #pragma unroll
        for (int di = 0; di < 3; ++di) {
            #pragma unroll
            for (int dj = 0; dj < 3; ++dj) {
                acc += s_f[kc * 16 + k][di][lx + dj]
                     * Wp[(size_t)(k * 9 + di * 3 + dj) * 192];
            }
        }
    }
    s_red[kc][lw] = acc;
    __syncthreads();
    if (kc == 0) {
        float v = s_red[0][lw] + s_red[1][lw] + s_red[2][lw] + s_red[3][lw];
        int o = h * 192 + w;
        out[o] = v;
        out[36864 + o] = v;
        out[2 * 36864 + o] = v;
    }
}

// ---------------------------------------------------------------------------
extern "C" void kernel_launch(void* const* d_in, const int* in_sizes, int n_in,
                              void* d_out, int out_size, void* d_ws, size_t ws_size,
                              hipStream_t stream)
{
    const float* x     = (const float*)d_in[0];
    const float* c1_w  = (const float*)d_in[1];
    const float* c1_b  = (const float*)d_in[2];
    const float* dbw[5] = {(const float*)d_in[3], (const float*)d_in[5],
                           (const float*)d_in[7], (const float*)d_in[9],
                           (const float*)d_in[11]};
    const float* dbb[5] = {(const float*)d_in[4], (const float*)d_in[6],
                           (const float*)d_in[8], (const float*)d_in[10],
                           (const float*)d_in[12]};
    const float* c2_w  = (const float*)d_in[13];
    const float* c2_b  = (const float*)d_in[14];
    const float* fc1_w = (const float*)d_in[15];
    const float* fc1_b = (const float*)d_in[16];
    const float* fc2_w = (const float*)d_in[17];
    const float* fc2_b = (const float*)d_in[18];

    float* ws   = (float*)d_ws;
    float* x0   = ws;
    float* feat = ws + (size_t)NPIX;
    float* hA   = ws + 2 * (size_t)NPIX;
    float* hB   = ws + 3 * (size_t)NPIX;
    float* gbuf = ws + 4 * (size_t)NPIX;
    float* WtT  = ws + 5 * (size_t)NPIX;   // 1728*192 floats

    const int ICs[5]     = {64, 80, 96, 112, 128};
    const int wstride[5] = {9216, 11520, 13824, 16128, 73728};
    const int bstride[5] = {16, 16, 16, 16, 64};

    // c1: 3 -> 64
    conv3x3_k<<<dim3(144, 4), 256, 0, stream>>>(x, 3, nullptr, c1_w, c1_b, 3,
                                                x0, 0, 1.f, nullptr, 0.f, nullptr, 0.f);

    for (int blk = 0; blk < 4; ++blk) {
        const float* featin = (blk == 0) ? x0 : feat;   // RRDB input
        for (int db = 0; db < 3; ++db) {
            int d = blk * 3 + db;
            const float* base = (db == 0) ? featin : ((db == 1) ? hA : hB);
            // convs 1..4 (lrelu, 16 out ch) into gbuf growth channels
            for (int cv = 0; cv < 4; ++cv) {
                conv3x3_k<<<dim3(144, 1), 256, 0, stream>>>(
                    base, 64, gbuf,
                    dbw[cv] + (size_t)d * wstride[cv],
                    dbb[cv] + (size_t)d * bstride[cv],
                    ICs[cv], gbuf + (size_t)cv * 16 * HW,
                    1, 1.f, nullptr, 0.f, nullptr, 0.f);
            }
            // conv5 (no lrelu) with fused residuals
            if (db < 2) {
                // h_next = conv*0.2 + base
                conv3x3_k<<<dim3(144, 4), 256, 0, stream>>>(
                    base, 64, gbuf,
                    dbw[4] + (size_t)d * wstride[4],
                    dbb[4] + (size_t)d * bstride[4],
                    128, (db == 0) ? hA : hB, 0, 0.2f, base, 1.f, nullptr, 0.f);
            } else {
                // feat = (conv*0.2 + hB)*0.2 + featin = conv*0.04 + hB*0.2 + featin
                conv3x3_k<<<dim3(144, 4), 256, 0, stream>>>(
                    base, 64, gbuf,
                    dbw[4] + (size_t)d * wstride[4],
                    dbb[4] + (size_t)d * bstride[4],
                    128, feat, 0, 0.04f, hB, 0.2f, featin, 1.f);
            }
        }
    }

    // feat_final = conv(feat, c2) + x0  -> hA
    conv3x3_k<<<dim3(144, 4), 256, 0, stream>>>(feat, 64, nullptr, c2_w, c2_b,
                                                64, hA, 0, 1.f, x0, 1.f, nullptr, 0.f);

    // dynamic-filter weights (192 distinct rows), transposed
    mlp_weights_k<<<192, 256, 0, stream>>>(fc1_w, fc1_b, fc2_w, fc2_b, WtT);

    // final gather-multiply-reduce
    dynfilter_k<<<dim3(3, 192), 256, 0, stream>>>(hA, WtT, (float*)d_out);
}

// Round 3
// 1367.349 us; speedup vs baseline: 3.0184x; 2.0005x over previous
//
#include <hip/hip_runtime.h>

#define Hh 96
#define Ww 96
#define HW 9216
#define NPIX 589824   // 9216*64

typedef __attribute__((ext_vector_type(8))) short bf16x8;
typedef __attribute__((ext_vector_type(4))) float f32x4;

__device__ __forceinline__ unsigned short f2bf(float f) {
    unsigned int u = __float_as_uint(f);
    u += 0x7fff + ((u >> 16) & 1);          // RNE
    return (unsigned short)(u >> 16);
}

// ---------------------------------------------------------------------------
// Weight prep: fp32 OIHW -> bf16 [tap][oc][ICp] per conv, ICp zero-padded.
// Dense-block segment (per d): cv0 9216, cv1 13824, cv2 13824, cv3 18432,
// cv4 73728 halfwords (total 129024); then c2 36864.
// ---------------------------------------------------------------------------
__global__ __launch_bounds__(256) void prep_w_k(
    const float* __restrict__ w0, const float* __restrict__ w1,
    const float* __restrict__ w2, const float* __restrict__ w3,
    const float* __restrict__ w4, const float* __restrict__ c2w,
    unsigned short* __restrict__ wb)
{
    int idx = blockIdx.x * 256 + threadIdx.x;
    const int DBSZ = 129024, TOT_DB = 12 * 129024;
    if (idx >= TOT_DB + 36864) return;
    float val;
    if (idx < TOT_DB) {
        int d = idx / DBSZ, rem = idx - d * DBSZ;
        int base, OC, IC, ICp; const float* wp;
        if      (rem < 9216)  { base = 0;     OC = 16; IC = 64;  ICp = 64;  wp = w0; }
        else if (rem < 23040) { base = 9216;  OC = 16; IC = 80;  ICp = 96;  wp = w1; }
        else if (rem < 36864) { base = 23040; OC = 16; IC = 96;  ICp = 96;  wp = w2; }
        else if (rem < 55296) { base = 36864; OC = 16; IC = 112; ICp = 128; wp = w3; }
        else                  { base = 55296; OC = 64; IC = 128; ICp = 128; wp = w4; }
        int e   = rem - base;
        int tap = e / (OC * ICp);
        int r   = e - tap * (OC * ICp);
        int oc  = r / ICp, icp = r - oc * ICp;
        val = (icp < IC) ? wp[(((size_t)d * OC + oc) * IC + icp) * 9 + tap] : 0.f;
    } else {
        int e = idx - TOT_DB;
        int tap = e / 4096, r = e & 4095;
        int oc = r >> 6, icp = r & 63;
        val = c2w[((size_t)(oc * 64 + icp)) * 9 + tap];
    }
    wb[idx] = f2bf(val);
}

// ---------------------------------------------------------------------------
// c1: 3->64 conv from NCHW fp32 x; writes x0f (fp32 NHWC) + dba ch0..63 (bf16)
// ---------------------------------------------------------------------------
__global__ __launch_bounds__(256) void c1_k(
    const float* __restrict__ x, const float* __restrict__ w,
    const float* __restrict__ bias,
    float* __restrict__ x0f, unsigned short* __restrict__ dba)
{
    __shared__ float sw[1728];
    __shared__ float sb[64];
    int tid = threadIdx.x;
    for (int i = tid; i < 1728; i += 256) sw[i] = w[i];
    if (tid < 64) sb[tid] = bias[tid];
    __syncthreads();
    int px = blockIdx.x * 256 + tid;
    int gy = px / 96, gx = px - (px / 96) * 96;
    float in[3][3][3];
    #pragma unroll
    for (int c = 0; c < 3; ++c)
        #pragma unroll
        for (int dy = 0; dy < 3; ++dy)
            #pragma unroll
            for (int dx = 0; dx < 3; ++dx) {
                int yy = gy - 1 + dy, xx = gx - 1 + dx;
                in[c][dy][dx] = (yy >= 0 && yy < 96 && xx >= 0 && xx < 96)
                                ? x[c * HW + yy * 96 + xx] : 0.f;
            }
    for (int oc = 0; oc < 64; ++oc) {
        float acc = sb[oc];
        const float* wp = &sw[oc * 27];
        #pragma unroll
        for (int c = 0; c < 3; ++c)
            #pragma unroll
            for (int dy = 0; dy < 3; ++dy)
                #pragma unroll
                for (int dx = 0; dx < 3; ++dx)
                    acc += wp[(c * 3 + dy) * 3 + dx] * in[c][dy][dx];
        x0f[(size_t)px * 64 + oc] = acc;
        dba[(size_t)px * 128 + oc] = f2bf(acc);
    }
}

// ---------------------------------------------------------------------------
// MFMA 3x3 conv (tap-GEMM): D[oc][px] += sum_tap W_tap[oc][ic] * X_tap[ic][px]
//  - act: bf16 NHWC [9216][cstride], reads channel prefix [0,IC)
//  - wb:  bf16 [9][OC][ICp]
//  - block: 256 thr = 4 waves; 8x8 px tile; OC=64: wave=M-tile; OC=16: wave=N-tile
//  - epilogue: v = act(acc+bias); v = alpha*v + beta*r1 + gamma*r2 (fp32 NHWC)
//    writes bf16 out (at channel offset) and/or fp32 NHWC out
// ---------------------------------------------------------------------------
__global__ __launch_bounds__(256) void conv_mfma_k(
    const unsigned short* __restrict__ act, int cstride, int IC, int ICp,
    const unsigned short* __restrict__ wb,
    const float* __restrict__ bias, int OC,
    int do_lrelu, float alpha,
    const float* __restrict__ r1, float beta,
    const float* __restrict__ r2, float gamma,
    unsigned short* out_bf, int out_choff, int out_cstride,
    float* out_fp)
{
    const int tile = blockIdx.x;
    const int tx0 = (tile % 12) * 8, ty0 = (tile / 12) * 8;
    const int tid = threadIdx.x;
    const int wid = tid >> 6, lane = tid & 63;
    const int l16 = lane & 15, q = lane >> 4;

    __shared__ unsigned short s[10 * 10 * 40];   // [row][col][40], ic in 0..31

    const int MT  = OC >> 4;                      // 1 or 4
    const int mt  = (MT == 4) ? wid : 0;
    const int ntA = (MT == 4) ? 0 : wid;
    const int ntN = (MT == 4) ? 4 : 1;

    f32x4 acc[4];
    #pragma unroll
    for (int i = 0; i < 4; ++i) acc[i] = (f32x4){0.f, 0.f, 0.f, 0.f};

    for (int icb = 0; icb < ICp; icb += 32) {
        for (int i = tid; i < 3200; i += 256) {
            int ic = i & 31, p = i >> 5;
            int row = p / 10, col = p - row * 10;
            int gy = ty0 - 1 + row, gx = tx0 - 1 + col;
            int gc = icb + ic;
            unsigned short v = 0;
            if (gy >= 0 && gy < 96 && gx >= 0 && gx < 96 && gc < IC)
                v = act[(size_t)(gy * 96 + gx) * cstride + gc];
            s[(row * 10 + col) * 40 + ic] = v;
        }
        __syncthreads();

        #pragma unroll
        for (int tap = 0; tap < 9; ++tap) {
            const int dy = tap / 3, dx = tap - dy * 3;
            bf16x8 a = *(const bf16x8*)&wb[((size_t)(tap * OC + mt * 16 + l16)) * ICp + icb + q * 8];
            for (int nt = 0; nt < ntN; ++nt) {
                int px = (ntA + nt) * 16 + l16;
                int yy = px >> 3, xx = px & 7;
                bf16x8 b = *(const bf16x8*)&s[((yy + dy) * 10 + (xx + dx)) * 40 + q * 8];
                acc[nt] = __builtin_amdgcn_mfma_f32_16x16x32_bf16(a, b, acc[nt], 0, 0, 0);
            }
        }
        __syncthreads();
    }

    const float4 bv = *(const float4*)&bias[mt * 16 + q * 4];
    for (int nt = 0; nt < ntN; ++nt) {
        int px = (ntA + nt) * 16 + l16;
        size_t pix = (size_t)((ty0 + (px >> 3)) * 96 + tx0 + (px & 7));
        int ocb = mt * 16 + q * 4;
        float4 res1, res2;
        if (r1) res1 = *(const float4*)&r1[pix * 64 + ocb];
        if (r2) res2 = *(const float4*)&r2[pix * 64 + ocb];
        float vv[4];
        #pragma unroll
        for (int r = 0; r < 4; ++r) {
            float v = acc[nt][r] + ((const float*)&bv)[r];
            if (do_lrelu) v = (v > 0.f) ? v : 0.2f * v;
            v *= alpha;
            if (r1) v += beta  * ((const float*)&res1)[r];
            if (r2) v += gamma * ((const float*)&res2)[r];
            vv[r] = v;
        }
        if (out_bf) {
            ushort4 o;
            o.x = f2bf(vv[0]); o.y = f2bf(vv[1]); o.z = f2bf(vv[2]); o.w = f2bf(vv[3]);
            *(ushort4*)&out_bf[pix * out_cstride + out_choff + ocb] = o;
        }
        if (out_fp) {
            float4 o = {vv[0], vv[1], vv[2], vv[3]};
            *(float4*)&out_fp[pix * 64 + ocb] = o;
        }
    }
}

// ---------------------------------------------------------------------------
// MLP collapsed to 192 distinct rows; WtT[f][t]
// ---------------------------------------------------------------------------
__global__ __launch_bounds__(256) void mlp_weights_k(
    const float* __restrict__ fc1_w, const float* __restrict__ fc1_b,
    const float* __restrict__ fc2_w, const float* __restrict__ fc2_b,
    float* __restrict__ WtT)
{
    const int t = blockIdx.x, tid = threadIdx.x;
    __shared__ float h1[256];
    float tt = (float)t;
    float v = tt * fc1_w[tid] + tt * fc1_w[256 + tid] + 2.0f * fc1_w[512 + tid]
              + fc1_b[tid];
    h1[tid] = (v > 0.f) ? v : 0.2f * v;
    __syncthreads();
    for (int f = tid; f < 1728; f += 256) {
        float acc = fc2_b[f];
        for (int j = 0; j < 256; ++j)
            acc += h1[j] * fc2_w[(size_t)j * 1728 + f];
        WtT[(size_t)f * 192 + t] = acc;
    }
}

// ---------------------------------------------------------------------------
// Final dynamic-filter gather; feat is fp32 NHWC [9216][64]
// ---------------------------------------------------------------------------
__global__ __launch_bounds__(256) void dynfilter_k(
    const float* __restrict__ feat,
    const float* __restrict__ WtT,
    float* __restrict__ out)
{
    const int h   = blockIdx.y;
    const int w0  = blockIdx.x * 64;
    const int tid = threadIdx.x;
    const int lw  = tid & 63, kc = tid >> 6;
    const int ybase = h / 2 - 1;
    const int x0lo  = w0 / 2 - 1;

    __shared__ float s_f[64][3][36];
    __shared__ float s_red[4][64];

    for (int i = tid; i < 64 * 102; i += 256) {
        int k = i & 63, j = i >> 6;          // j 0..101
        int di = j / 34, col = j - di * 34;
        int yv = ybase + di, xv = x0lo + col;
        float v = 0.f;
        if (yv >= 0 && yv < Hh && xv >= 0 && xv < Ww)
            v = feat[(size_t)(yv * Ww + xv) * 64 + k];
        s_f[k][di][col] = v;
    }
    __syncthreads();

    const int w = w0 + lw;
    const int qq = w % 3;
    const int t = (h % 3) * 64 + w / 3;
    const int lx = (w / 2 - 1) - x0lo;
    const float* Wp = WtT + (size_t)(qq * 576 + kc * 144) * 192 + t;
    float acc = 0.f;
    for (int k = 0; k < 16; ++k) {
        #pragma unroll
        for (int di = 0; di < 3; ++di)
            #pragma unroll
            for (int dj = 0; dj < 3; ++dj)
                acc += s_f[kc * 16 + k][di][lx + dj]
                     * Wp[(size_t)(k * 9 + di * 3 + dj) * 192];
    }
    s_red[kc][lw] = acc;
    __syncthreads();
    if (kc == 0) {
        float v = s_red[0][lw] + s_red[1][lw] + s_red[2][lw] + s_red[3][lw];
        int o = h * 192 + w;
        out[o] = v;
        out[36864 + o] = v;
        out[2 * 36864 + o] = v;
    }
}

// ---------------------------------------------------------------------------
extern "C" void kernel_launch(void* const* d_in, const int* in_sizes, int n_in,
                              void* d_out, int out_size, void* d_ws, size_t ws_size,
                              hipStream_t stream)
{
    const float* x     = (const float*)d_in[0];
    const float* c1_w  = (const float*)d_in[1];
    const float* c1_b  = (const float*)d_in[2];
    const float* dbw[5] = {(const float*)d_in[3], (const float*)d_in[5],
                           (const float*)d_in[7], (const float*)d_in[9],
                           (const float*)d_in[11]};
    const float* dbb[5] = {(const float*)d_in[4], (const float*)d_in[6],
                           (const float*)d_in[8], (const float*)d_in[10],
                           (const float*)d_in[12]};
    const float* c2_w  = (const float*)d_in[13];
    const float* c2_b  = (const float*)d_in[14];
    const float* fc1_w = (const float*)d_in[15];
    const float* fc1_b = (const float*)d_in[16];
    const float* fc2_w = (const float*)d_in[17];
    const float* fc2_b = (const float*)d_in[18];

    float* ws    = (float*)d_ws;
    float* x0f   = ws;                    // [9216][64] fp32
    float* hfA   = ws + (size_t)NPIX;     // h fp32 ping ; later: final feat (ff)
    float* hfB   = ws + 2 * (size_t)NPIX; // h fp32 pong
    float* featf = ws + 3 * (size_t)NPIX; // RRDB-residual feat fp32
    unsigned short* dbaA = (unsigned short*)(ws + 4 * (size_t)NPIX); // [9216][128] bf16
    unsigned short* dbaB = dbaA + (size_t)9216 * 128;
    unsigned short* wb   = dbaB + (size_t)9216 * 128;                // 1585152 hw
    float* ff  = hfA;                      // final feature (after all h uses)
    float* WtT = (float*)dbaA;             // aliases dbaA after trunk is done

    const int ICt[4]   = {64, 80, 96, 112};
    const int ICpt[4]  = {64, 96, 96, 128};
    const int wbase[4] = {0, 9216, 23040, 36864};

    prep_w_k<<<6192, 256, 0, stream>>>(dbw[0], dbw[1], dbw[2], dbw[3], dbw[4],
                                       c2_w, wb);
    c1_k<<<36, 256, 0, stream>>>(x, c1_w, c1_b, x0f, dbaA);

    for (int d = 0; d < 12; ++d) {
        unsigned short* in   = (d & 1) ? dbaB : dbaA;
        unsigned short* outb = (d & 1) ? dbaA : dbaB;
        for (int cv = 0; cv < 4; ++cv) {
            conv_mfma_k<<<144, 256, 0, stream>>>(
                in, 128, ICt[cv], ICpt[cv],
                wb + (size_t)d * 129024 + wbase[cv],
                dbb[cv] + (size_t)d * 16, 16,
                1, 1.f, nullptr, 0.f, nullptr, 0.f,
                in, 64 + cv * 16, 128, nullptr);
        }
        int pos = d % 3;
        const float* featprev = (d < 3) ? x0f : featf;
        const unsigned short* wseg = wb + (size_t)d * 129024 + 55296;
        const float* b5 = dbb[4] + (size_t)d * 64;
        if (pos == 0)
            conv_mfma_k<<<144, 256, 0, stream>>>(in, 128, 128, 128, wseg, b5, 64,
                0, 0.2f, featprev, 1.f, nullptr, 0.f, outb, 0, 128, hfA);
        else if (pos == 1)
            conv_mfma_k<<<144, 256, 0, stream>>>(in, 128, 128, 128, wseg, b5, 64,
                0, 0.2f, hfA, 1.f, nullptr, 0.f, outb, 0, 128, hfB);
        else
            conv_mfma_k<<<144, 256, 0, stream>>>(in, 128, 128, 128, wseg, b5, 64,
                0, 0.04f, hfB, 0.2f, featprev, 1.f, outb, 0, 128, featf);
    }

    // c2: input = dbaA (d=11 wrote it); ff = conv + x0
    conv_mfma_k<<<144, 256, 0, stream>>>(dbaA, 128, 64, 64,
        wb + (size_t)12 * 129024, c2_b, 64,
        0, 1.f, x0f, 1.f, nullptr, 0.f, nullptr, 0, 128, ff);

    mlp_weights_k<<<192, 256, 0, stream>>>(fc1_w, fc1_b, fc2_w, fc2_b, WtT);
    dynfilter_k<<<dim3(3, 192), 256, 0, stream>>>(ff, WtT, (float*)d_out);
}

// Round 4
// 532.453 us; speedup vs baseline: 7.7513x; 2.5680x over previous
//
#include <hip/hip_runtime.h>

#define Hh 96
#define Ww 96
#define HW 9216
#define NPIX 589824   // 9216*64

typedef __attribute__((ext_vector_type(8))) short bf16x8;
typedef __attribute__((ext_vector_type(4))) float f32x4;

__device__ __forceinline__ unsigned short f2bf(float f) {
    unsigned int u = __float_as_uint(f);
    u += 0x7fff + ((u >> 16) & 1);          // RNE
    return (unsigned short)(u >> 16);
}

// ---------------------------------------------------------------------------
// Weight prep: fp32 OIHW -> bf16 [tap][oc][ICp] per conv, ICp zero-padded.
// ---------------------------------------------------------------------------
__global__ __launch_bounds__(256) void prep_w_k(
    const float* __restrict__ w0, const float* __restrict__ w1,
    const float* __restrict__ w2, const float* __restrict__ w3,
    const float* __restrict__ w4, const float* __restrict__ c2w,
    unsigned short* __restrict__ wb)
{
    int idx = blockIdx.x * 256 + threadIdx.x;
    const int DBSZ = 129024, TOT_DB = 12 * 129024;
    if (idx >= TOT_DB + 36864) return;
    float val;
    if (idx < TOT_DB) {
        int d = idx / DBSZ, rem = idx - d * DBSZ;
        int base, OC, IC, ICp; const float* wp;
        if      (rem < 9216)  { base = 0;     OC = 16; IC = 64;  ICp = 64;  wp = w0; }
        else if (rem < 23040) { base = 9216;  OC = 16; IC = 80;  ICp = 96;  wp = w1; }
        else if (rem < 36864) { base = 23040; OC = 16; IC = 96;  ICp = 96;  wp = w2; }
        else if (rem < 55296) { base = 36864; OC = 16; IC = 112; ICp = 128; wp = w3; }
        else                  { base = 55296; OC = 64; IC = 128; ICp = 128; wp = w4; }
        int e   = rem - base;
        int tap = e / (OC * ICp);
        int r   = e - tap * (OC * ICp);
        int oc  = r / ICp, icp = r - oc * ICp;
        val = (icp < IC) ? wp[(((size_t)d * OC + oc) * IC + icp) * 9 + tap] : 0.f;
    } else {
        int e = idx - TOT_DB;
        int tap = e / 4096, r = e & 4095;
        int oc = r >> 6, icp = r & 63;
        val = c2w[((size_t)(oc * 64 + icp)) * 9 + tap];
    }
    wb[idx] = f2bf(val);
}

// ---------------------------------------------------------------------------
// c1: 3->64 conv from NCHW fp32 x; writes x0f (fp32 NHWC) + dba ch0..63 (bf16)
// ---------------------------------------------------------------------------
__global__ __launch_bounds__(256) void c1_k(
    const float* __restrict__ x, const float* __restrict__ w,
    const float* __restrict__ bias,
    float* __restrict__ x0f, unsigned short* __restrict__ dba)
{
    __shared__ float sw[1728];
    __shared__ float sb[64];
    int tid = threadIdx.x;
    for (int i = tid; i < 1728; i += 256) sw[i] = w[i];
    if (tid < 64) sb[tid] = bias[tid];
    __syncthreads();
    int px = blockIdx.x * 256 + tid;
    int gy = px / 96, gx = px - (px / 96) * 96;
    float in[3][3][3];
    #pragma unroll
    for (int c = 0; c < 3; ++c)
        #pragma unroll
        for (int dy = 0; dy < 3; ++dy)
            #pragma unroll
            for (int dx = 0; dx < 3; ++dx) {
                int yy = gy - 1 + dy, xx = gx - 1 + dx;
                in[c][dy][dx] = (yy >= 0 && yy < 96 && xx >= 0 && xx < 96)
                                ? x[c * HW + yy * 96 + xx] : 0.f;
            }
    for (int oc = 0; oc < 64; ++oc) {
        float acc = sb[oc];
        const float* wp = &sw[oc * 27];
        #pragma unroll
        for (int c = 0; c < 3; ++c)
            #pragma unroll
            for (int dy = 0; dy < 3; ++dy)
                #pragma unroll
                for (int dx = 0; dx < 3; ++dx)
                    acc += wp[(c * 3 + dy) * 3 + dx] * in[c][dy][dx];
        x0f[(size_t)px * 64 + oc] = acc;
        dba[(size_t)px * 128 + oc] = f2bf(acc);
    }
}

// ---------------------------------------------------------------------------
// MFMA 3x3 conv (tap-GEMM), 8x4 px tile, 288 blocks, single staging barrier.
//  - act: bf16 NHWC [9216][cstride], channel prefix [0,IC)
//  - wb:  bf16 [9][OC][ICp]
//  - OC=64: wave=mt (16 oc), 2 nt px-frags each
//  - OC=16: wave = (nt 2) x (K-half 2), LDS reduction
// ---------------------------------------------------------------------------
__global__ __launch_bounds__(256) void conv_mfma_k(
    const unsigned short* __restrict__ act, int cstride, int IC, int ICp,
    const unsigned short* __restrict__ wb,
    const float* __restrict__ bias, int OC,
    int do_lrelu, float alpha,
    const float* __restrict__ r1, float beta,
    const float* __restrict__ r2, float gamma,
    unsigned short* out_bf, int out_choff, int out_cstride,
    float* out_fp)
{
    const int tile = blockIdx.x;             // 0..287
    const int tx0 = (tile % 12) * 8, ty0 = (tile / 12) * 4;
    const int tid = threadIdx.x;
    const int wid = tid >> 6, lane = tid & 63;
    const int l16 = lane & 15, q = lane >> 4;
    const int stride = ICp + 8;              // ushorts; 2-way-free banks

    __shared__ unsigned short s[60 * 136];
    __shared__ float red[32 * 16];

    // stage entire halo (6 rows x 10 cols x ICp) as 16B granules
    const int NG = ICp >> 3;
    for (int i = tid; i < 60 * NG; i += 256) {
        int hp = i / NG, g = i - hp * NG;
        int row = hp / 10, col = hp - row * 10;
        int gy = ty0 - 1 + row, gx = tx0 - 1 + col;
        int gc = g * 8;
        uint4 v = {0u, 0u, 0u, 0u};
        if (gy >= 0 && gy < 96 && gx >= 0 && gx < 96 && gc < IC)
            v = *reinterpret_cast<const uint4*>(
                    &act[(size_t)(gy * 96 + gx) * cstride + gc]);
        *reinterpret_cast<uint4*>(&s[hp * stride + gc]) = v;
    }
    __syncthreads();

    if (OC == 64) {
        const int mt = wid;
        f32x4 acc0 = {0.f, 0.f, 0.f, 0.f}, acc1 = {0.f, 0.f, 0.f, 0.f};
        const int arow = (mt * 16 + l16) * ICp + q * 8;
        const int yy0 = l16 >> 3, xx0 = l16 & 7;        // nt=0 px
        const int yy1 = 2 + (l16 >> 3), xx1 = l16 & 7;  // nt=1 px
        for (int icb = 0; icb < ICp; icb += 32) {
            #pragma unroll
            for (int tap = 0; tap < 9; ++tap) {
                const int dy = tap / 3, dx = tap - dy * 3;
                bf16x8 a = *(const bf16x8*)&wb[(size_t)tap * 64 * ICp + arow + icb];
                bf16x8 b0 = *(const bf16x8*)&s[((yy0 + dy) * 10 + xx0 + dx) * stride + icb + q * 8];
                acc0 = __builtin_amdgcn_mfma_f32_16x16x32_bf16(a, b0, acc0, 0, 0, 0);
                bf16x8 b1 = *(const bf16x8*)&s[((yy1 + dy) * 10 + xx1 + dx) * stride + icb + q * 8];
                acc1 = __builtin_amdgcn_mfma_f32_16x16x32_bf16(a, b1, acc1, 0, 0, 0);
            }
        }
        const float4 bv = *(const float4*)&bias[mt * 16 + q * 4];
        #pragma unroll
        for (int nt = 0; nt < 2; ++nt) {
            f32x4 acc = nt ? acc1 : acc0;
            int p = nt * 16 + l16;
            size_t pix = (size_t)((ty0 + (p >> 3)) * 96 + tx0 + (p & 7));
            int ocb = mt * 16 + q * 4;
            float4 res1, res2;
            if (r1) res1 = *(const float4*)&r1[pix * 64 + ocb];
            if (r2) res2 = *(const float4*)&r2[pix * 64 + ocb];
            float vv[4];
            #pragma unroll
            for (int r = 0; r < 4; ++r) {
                float v = acc[r] + ((const float*)&bv)[r];
                if (do_lrelu) v = (v > 0.f) ? v : 0.2f * v;
                v *= alpha;
                if (r1) v += beta  * ((const float*)&res1)[r];
                if (r2) v += gamma * ((const float*)&res2)[r];
                vv[r] = v;
            }
            if (out_bf) {
                ushort4 o;
                o.x = f2bf(vv[0]); o.y = f2bf(vv[1]); o.z = f2bf(vv[2]); o.w = f2bf(vv[3]);
                *(ushort4*)&out_bf[pix * out_cstride + out_choff + ocb] = o;
            }
            if (out_fp) {
                float4 o = {vv[0], vv[1], vv[2], vv[3]};
                *(float4*)&out_fp[pix * 64 + ocb] = o;
            }
        }
    } else {                                  // OC == 16
        const int nt = wid & 1, kh = wid >> 1;
        f32x4 acc = {0.f, 0.f, 0.f, 0.f};
        const int arow = l16 * ICp + q * 8;
        const int yy = nt * 2 + (l16 >> 3), xx = l16 & 7;
        for (int icb = kh * 32; icb < ICp; icb += 64) {
            #pragma unroll
            for (int tap = 0; tap < 9; ++tap) {
                const int dy = tap / 3, dx = tap - dy * 3;
                bf16x8 a = *(const bf16x8*)&wb[(size_t)tap * 16 * ICp + arow + icb];
                bf16x8 b = *(const bf16x8*)&s[((yy + dy) * 10 + xx + dx) * stride + icb + q * 8];
                acc = __builtin_amdgcn_mfma_f32_16x16x32_bf16(a, b, acc, 0, 0, 0);
            }
        }
        const int p = nt * 16 + l16;
        if (kh == 1)
            *(f32x4*)&red[p * 16 + q * 4] = acc;
        __syncthreads();
        if (kh == 0) {
            f32x4 o = *(const f32x4*)&red[p * 16 + q * 4];
            const float4 bv = *(const float4*)&bias[q * 4];
            size_t pix = (size_t)((ty0 + (p >> 3)) * 96 + tx0 + (p & 7));
            ushort4 ov;
            float vv[4];
            #pragma unroll
            for (int r = 0; r < 4; ++r) {
                float v = acc[r] + o[r] + ((const float*)&bv)[r];
                v = (v > 0.f) ? v : 0.2f * v;       // growth convs always lrelu
                vv[r] = v;
            }
            ov.x = f2bf(vv[0]); ov.y = f2bf(vv[1]); ov.z = f2bf(vv[2]); ov.w = f2bf(vv[3]);
            *(ushort4*)&out_bf[pix * out_cstride + out_choff + q * 4] = ov;
        }
    }
}

// ---------------------------------------------------------------------------
// MLP: WtT[f][t] = fc2_b[f] + sum_j lrelu(a[j]*t + c[j]) * fc2_w[j][f]
// a[j] = fc1_w[0][j]+fc1_w[1][j], c[j] = 2*fc1_w[2][j]+fc1_b[j]
// grid (27 f-tiles, 3 t-tiles); thread = 4f x 4t register tile.
// ---------------------------------------------------------------------------
__global__ __launch_bounds__(256) void mlp_k(
    const float* __restrict__ fc1_w, const float* __restrict__ fc1_b,
    const float* __restrict__ fc2_w, const float* __restrict__ fc2_b,
    float* __restrict__ WtT)
{
    const int f0 = blockIdx.x * 64, t0 = blockIdx.y * 64;
    const int tid = threadIdx.x;
    const int ft = tid & 15, tt = tid >> 4;
    __shared__ float sa[256], sc[256];
    __shared__ float swt[64][64];
    sa[tid] = fc1_w[tid] + fc1_w[256 + tid];
    sc[tid] = 2.f * fc1_w[512 + tid] + fc1_b[tid];
    float acc[4][4] = {};
    const float tbase = (float)(t0 + tt * 4);
    for (int jc = 0; jc < 256; jc += 64) {
        __syncthreads();
        for (int i = tid; i < 4096; i += 256) {
            int j = i >> 6, f = i & 63;
            swt[j][f] = fc2_w[(size_t)(jc + j) * 1728 + f0 + f];
        }
        __syncthreads();
        for (int j = 0; j < 64; ++j) {
            float4 wv = *(const float4*)&swt[j][ft * 4];
            float aj = sa[jc + j], cj = sc[jc + j];
            #pragma unroll
            for (int v = 0; v < 4; ++v) {
                float h = aj * (tbase + (float)v) + cj;
                h = (h > 0.f) ? h : 0.2f * h;
                acc[0][v] += h * wv.x;
                acc[1][v] += h * wv.y;
                acc[2][v] += h * wv.z;
                acc[3][v] += h * wv.w;
            }
        }
    }
    #pragma unroll
    for (int u = 0; u < 4; ++u) {
        int f = f0 + ft * 4 + u;
        float b = fc2_b[f];
        float4 o = {acc[u][0] + b, acc[u][1] + b, acc[u][2] + b, acc[u][3] + b};
        *(float4*)&WtT[(size_t)f * 192 + t0 + tt * 4] = o;
    }
}

// ---------------------------------------------------------------------------
// Final dynamic-filter gather; feat is fp32 NHWC [9216][64]
// ---------------------------------------------------------------------------
__global__ __launch_bounds__(256) void dynfilter_k(
    const float* __restrict__ feat,
    const float* __restrict__ WtT,
    float* __restrict__ out)
{
    const int h   = blockIdx.y;
    const int w0  = blockIdx.x * 64;
    const int tid = threadIdx.x;
    const int lw  = tid & 63, kc = tid >> 6;
    const int ybase = h / 2 - 1;
    const int x0lo  = w0 / 2 - 1;

    __shared__ float s_f[64][3][36];
    __shared__ float s_red[4][64];

    for (int i = tid; i < 64 * 102; i += 256) {
        int k = i & 63, j = i >> 6;
        int di = j / 34, col = j - di * 34;
        int yv = ybase + di, xv = x0lo + col;
        float v = 0.f;
        if (yv >= 0 && yv < Hh && xv >= 0 && xv < Ww)
            v = feat[(size_t)(yv * Ww + xv) * 64 + k];
        s_f[k][di][col] = v;
    }
    __syncthreads();

    const int w = w0 + lw;
    const int qq = w % 3;
    const int t = (h % 3) * 64 + w / 3;
    const int lx = (w / 2 - 1) - x0lo;
    const float* Wp = WtT + (size_t)(qq * 576 + kc * 144) * 192 + t;
    float acc = 0.f;
    for (int k = 0; k < 16; ++k) {
        #pragma unroll
        for (int di = 0; di < 3; ++di)
            #pragma unroll
            for (int dj = 0; dj < 3; ++dj)
                acc += s_f[kc * 16 + k][di][lx + dj]
                     * Wp[(size_t)(k * 9 + di * 3 + dj) * 192];
    }
    s_red[kc][lw] = acc;
    __syncthreads();
    if (kc == 0) {
        float v = s_red[0][lw] + s_red[1][lw] + s_red[2][lw] + s_red[3][lw];
        int o = h * 192 + w;
        out[o] = v;
        out[36864 + o] = v;
        out[2 * 36864 + o] = v;
    }
}

// ---------------------------------------------------------------------------
extern "C" void kernel_launch(void* const* d_in, const int* in_sizes, int n_in,
                              void* d_out, int out_size, void* d_ws, size_t ws_size,
                              hipStream_t stream)
{
    const float* x     = (const float*)d_in[0];
    const float* c1_w  = (const float*)d_in[1];
    const float* c1_b  = (const float*)d_in[2];
    const float* dbw[5] = {(const float*)d_in[3], (const float*)d_in[5],
                           (const float*)d_in[7], (const float*)d_in[9],
                           (const float*)d_in[11]};
    const float* dbb[5] = {(const float*)d_in[4], (const float*)d_in[6],
                           (const float*)d_in[8], (const float*)d_in[10],
                           (const float*)d_in[12]};
    const float* c2_w  = (const float*)d_in[13];
    const float* c2_b  = (const float*)d_in[14];
    const float* fc1_w = (const float*)d_in[15];
    const float* fc1_b = (const float*)d_in[16];
    const float* fc2_w = (const float*)d_in[17];
    const float* fc2_b = (const float*)d_in[18];

    float* ws    = (float*)d_ws;
    float* x0f   = ws;                    // [9216][64] fp32
    float* hfA   = ws + (size_t)NPIX;
    float* hfB   = ws + 2 * (size_t)NPIX;
    float* featf = ws + 3 * (size_t)NPIX;
    unsigned short* dbaA = (unsigned short*)(ws + 4 * (size_t)NPIX); // [9216][128] bf16
    unsigned short* dbaB = dbaA + (size_t)9216 * 128;
    unsigned short* wb   = dbaB + (size_t)9216 * 128;
    float* ff  = hfA;
    float* WtT = (float*)dbaA;            // aliases dbaA after trunk done

    const int ICt[4]   = {64, 80, 96, 112};
    const int ICpt[4]  = {64, 96, 96, 128};
    const int wbase[4] = {0, 9216, 23040, 36864};

    prep_w_k<<<6192, 256, 0, stream>>>(dbw[0], dbw[1], dbw[2], dbw[3], dbw[4],
                                       c2_w, wb);
    c1_k<<<36, 256, 0, stream>>>(x, c1_w, c1_b, x0f, dbaA);

    for (int d = 0; d < 12; ++d) {
        unsigned short* in   = (d & 1) ? dbaB : dbaA;
        unsigned short* outb = (d & 1) ? dbaA : dbaB;
        for (int cv = 0; cv < 4; ++cv) {
            conv_mfma_k<<<288, 256, 0, stream>>>(
                in, 128, ICt[cv], ICpt[cv],
                wb + (size_t)d * 129024 + wbase[cv],
                dbb[cv] + (size_t)d * 16, 16,
                1, 1.f, nullptr, 0.f, nullptr, 0.f,
                in, 64 + cv * 16, 128, nullptr);
        }
        int pos = d % 3;
        const float* featprev = (d < 3) ? x0f : featf;
        const unsigned short* wseg = wb + (size_t)d * 129024 + 55296;
        const float* b5 = dbb[4] + (size_t)d * 64;
        if (pos == 0)
            conv_mfma_k<<<288, 256, 0, stream>>>(in, 128, 128, 128, wseg, b5, 64,
                0, 0.2f, featprev, 1.f, nullptr, 0.f, outb, 0, 128, hfA);
        else if (pos == 1)
            conv_mfma_k<<<288, 256, 0, stream>>>(in, 128, 128, 128, wseg, b5, 64,
                0, 0.2f, hfA, 1.f, nullptr, 0.f, outb, 0, 128, hfB);
        else
            conv_mfma_k<<<288, 256, 0, stream>>>(in, 128, 128, 128, wseg, b5, 64,
                0, 0.04f, hfB, 0.2f, featprev, 1.f, outb, 0, 128, featf);
    }

    // c2: ff = conv(dbaA) + x0
    conv_mfma_k<<<288, 256, 0, stream>>>(dbaA, 128, 64, 64,
        wb + (size_t)12 * 129024, c2_b, 64,
        0, 1.f, x0f, 1.f, nullptr, 0.f, nullptr, 0, 128, ff);

    mlp_k<<<dim3(27, 3), 256, 0, stream>>>(fc1_w, fc1_b, fc2_w, fc2_b, WtT);
    dynfilter_k<<<dim3(3, 192), 256, 0, stream>>>(ff, WtT, (float*)d_out);
}